// Round 6
// baseline (110.446 us; speedup 1.0000x reference)
//
#include <hip/hip_runtime.h>

#define NQ 6
#define DIM 64
#define NL 8

#define KP  136   // ws W row pitch (bf16 elems); 272 B rows keep 16B alignment
#define TPW 8     // tiles (of 16 samples) per wave; grid 512 x 256thr -> 2048 waves

typedef __attribute__((ext_vector_type(8))) short    short8v;   // 8 bf16 = 4 VGPRs
typedef __attribute__((ext_vector_type(4))) float    floatx4;
typedef __attribute__((ext_vector_type(4))) _Float16 half4v;    // 4 f16 = 2 VGPRs

__device__ inline short f2bf_rne(float f) {
    unsigned u = __float_as_uint(f);
    u += 0x7FFF + ((u >> 16) & 1);           // round-to-nearest-even
    return (short)(u >> 16);
}

// ---------------------------------------------------------------------------
// Prep (circuit verified rounds 1-5): build unitary U, emit to ws:
//   W[128][KP] bf16 : rows n<64 = Wr[n][*], n>=64 = Wi[n-64][*];
//                     cols k<64 = bf16_hi(W[n][k]), 64<=k<128 = bf16_lo(W[n][k])
//   M5h table (f16) at byte offset 128*KP*2: A-fragment-ready for
//   mfma_f32_16x16x16_f16: entry [c2][lane][j] = M5[c2*16+(lane>>4)*4+j][lane&15]
//   where M5[i][c<4] = sum_q sign(i,q) fc_w[c][q], M5[i][4] = 1, else 0.
// ---------------------------------------------------------------------------
__global__ __launch_bounds__(64) void qnn_prep(
    const float* __restrict__ wts,   // [8*6*3] (phi, theta, omega)
    const float* __restrict__ fc_w,  // [4*6]
    void* __restrict__ ws)
{
    __shared__ float gc[48][4];
    const int n   = threadIdx.x;     // amplitude row 0..63
    const int col = blockIdx.x;      // basis column 0..63

    if (n < 48) {
        float phi = wts[n*3+0], th = wts[n*3+1], om = wts[n*3+2];
        float ch = cosf(0.5f*th), sh = sinf(0.5f*th);
        float p  = 0.5f*(phi+om), m  = 0.5f*(phi-om);
        gc[n][0] = cosf(p)*ch;
        gc[n][1] = sinf(p)*ch;
        gc[n][2] = cosf(m)*sh;
        gc[n][3] = sinf(m)*sh;
    }
    __syncthreads();

    float ar = (n == col) ? 1.0f : 0.0f;
    float ai = 0.0f;

    #pragma unroll
    for (int l = 0; l < NL; ++l) {
        #pragma unroll
        for (int q = 0; q < NQ; ++q) {
            const int g     = l*NQ + q;
            const int shift = 5 - q;
            const int mask  = 1 << shift;
            const int b     = (n >> shift) & 1;
            const float cpch = gc[g][0];
            const float spch = gc[g][1];
            const float cmsh = gc[g][2];
            const float smsh = gc[g][3];
            const float pr = __shfl_xor(ar, mask, 64);
            const float pi = __shfl_xor(ai, mask, 64);
            const float udr = cpch;
            const float udi = b ?  spch : -spch;
            const float uor = b ?  cmsh : -cmsh;
            const float uoi = -smsh;
            const float nr = udr*ar - udi*ai + uor*pr - uoi*pi;
            const float ni = udr*ai + udi*ar + uor*pi + uoi*pr;
            ar = nr; ai = ni;
        }
        const int r = (l % (NQ - 1)) + 1;
        #pragma unroll
        for (int q = 0; q < NQ; ++q) {
            const int t     = (q + r) % NQ;
            const int cmask = 1 << (5 - q);
            const int tmask = 1 << (5 - t);
            const float pr = __shfl_xor(ar, tmask, 64);
            const float pi = __shfl_xor(ai, tmask, 64);
            const bool ctrl = (n & cmask) != 0;
            ar = ctrl ? pr : ar;
            ai = ctrl ? pi : ai;
        }
    }

    unsigned short* Bw = (unsigned short*)ws;
    unsigned short hr = (unsigned short)f2bf_rne(ar);
    float hrf = __uint_as_float((unsigned)hr << 16);
    unsigned short lr = (unsigned short)f2bf_rne(ar - hrf);
    unsigned short hi = (unsigned short)f2bf_rne(ai);
    float hif = __uint_as_float((unsigned)hi << 16);
    unsigned short li = (unsigned short)f2bf_rne(ai - hif);
    Bw[n*KP + col]           = hr;
    Bw[n*KP + 64 + col]      = lr;
    Bw[(64+n)*KP + col]      = hi;
    Bw[(64+n)*KP + 64 + col] = li;

    if (col == 0) {
        const int cp = n & 15;            // c' = l15
        const int qd = n >> 4;            // quad
        half4v* Mo = (half4v*)((char*)ws + 128*KP*2);
        #pragma unroll
        for (int c2 = 0; c2 < 4; ++c2) {
            half4v h4;
            #pragma unroll
            for (int j = 0; j < 4; ++j) {
                const int i = c2*16 + qd*4 + j;
                float v = 0.f;
                if (cp < 4) {
                    #pragma unroll
                    for (int q = 0; q < NQ; ++q) {
                        const float sgn = 1.0f - 2.0f*(float)((i >> (5-q)) & 1);
                        v = fmaf(sgn, fc_w[cp*NQ + q], v);
                    }
                } else if (cp == 4) {
                    v = 1.0f;             // ones column -> ss
                }
                h4[j] = (_Float16)v;
            }
            Mo[c2*64 + n] = h4;
        }
    }
}

// ---------------------------------------------------------------------------
// Main: NO LDS, NO barriers. 512 blocks x 256 thr (2 blocks/CU, 2 waves/EU).
// Each wave holds ALL of W (32 bf16 fragments = 128 VGPRs) + M5 fragments in
// registers for the kernel lifetime, then streams TPW tiles of 16 samples:
// coalesced float4 x-loads (register double-buffered, prefetch 1 tile ahead)
// -> bf16 convert -> 32x mfma_f32_16x16x32_bf16 -> f16-MFMA epilogue ->
// shfl_xor(16) for ss -> float4 store from quad-0 lanes.
// ---------------------------------------------------------------------------
__global__ __launch_bounds__(256, 2) void qnn_main(
    const float* __restrict__ x,
    const float* __restrict__ fc_b,
    const void* __restrict__ wsv,
    float* __restrict__ out)
{
    const int tid  = threadIdx.x;
    const int lane = tid & 63;
    const int w    = tid >> 6;
    const int l15  = lane & 15;
    const int quad = lane >> 4;
    const size_t gw = (size_t)blockIdx.x*4 + w;    // global wave id 0..2047

    // --- W fragments: A-layout [m=l15 -> W row mt*16+l15][k=kk*32+quad*8+j] ---
    const unsigned short* Wb = (const unsigned short*)wsv;
    short8v wfr[4][8];
    #pragma unroll
    for (int kk = 0; kk < 4; ++kk)
        #pragma unroll
        for (int mt = 0; mt < 8; ++mt)
            wfr[kk][mt] = *(const short8v*)(Wb + (mt*16 + l15)*KP + kk*32 + quad*8);

    // --- M5 epilogue A-fragments ---
    const half4v* Mg = (const half4v*)((const char*)wsv + 128*KP*2);
    half4v a2[4];
    #pragma unroll
    for (int c2 = 0; c2 < 4; ++c2) a2[c2] = Mg[c2*64 + lane];

    const float b0 = fc_b[0], b1 = fc_b[1], b2 = fc_b[2], b3 = fc_b[3];

    // lane's base pointer: sample row gw*TPW*16 + l15, cols quad*8..
    const float* xbase = x + (gw*TPW*16 + (size_t)l15)*DIM + quad*8;
    // tile t offset: t*16 rows = t*1024 floats

    float4 xr[2][4];

    // prologue: tile 0 -> buffer 0
    xr[0][0] = *(const float4*)(xbase);
    xr[0][1] = *(const float4*)(xbase + 4);
    xr[0][2] = *(const float4*)(xbase + 32);
    xr[0][3] = *(const float4*)(xbase + 36);

#define QNN_COMPUTE(BUF, TI)                                                   \
    {                                                                          \
        short8v xf[2];                                                         \
        _Pragma("unroll")                                                      \
        for (int h = 0; h < 2; ++h) {                                          \
            const float4 u0 = xr[BUF][2*h];                                    \
            const float4 u1 = xr[BUF][2*h + 1];                                \
            short8v a;                                                         \
            a[0]=f2bf_rne(u0.x); a[1]=f2bf_rne(u0.y);                          \
            a[2]=f2bf_rne(u0.z); a[3]=f2bf_rne(u0.w);                          \
            a[4]=f2bf_rne(u1.x); a[5]=f2bf_rne(u1.y);                          \
            a[6]=f2bf_rne(u1.z); a[7]=f2bf_rne(u1.w);                          \
            xf[h] = a;                                                         \
        }                                                                      \
        floatx4 acc[8];                                                        \
        _Pragma("unroll")                                                      \
        for (int mt = 0; mt < 8; ++mt) acc[mt] = (floatx4){0.f,0.f,0.f,0.f};   \
        _Pragma("unroll")                                                      \
        for (int kk = 0; kk < 4; ++kk) {                                       \
            const int h = kk & 1;                                              \
            _Pragma("unroll")                                                  \
            for (int mt = 0; mt < 8; ++mt)                                     \
                acc[mt] = __builtin_amdgcn_mfma_f32_16x16x32_bf16(             \
                    wfr[kk][mt], xf[h], acc[mt], 0, 0, 0);                     \
        }                                                                      \
        floatx4 d2 = (floatx4){0.f,0.f,0.f,0.f};                               \
        _Pragma("unroll")                                                      \
        for (int c2 = 0; c2 < 4; ++c2) {                                       \
            half4v pb;                                                         \
            _Pragma("unroll")                                                  \
            for (int r = 0; r < 4; ++r) {                                      \
                const float re = acc[c2][r];                                   \
                const float im = acc[c2 + 4][r];                               \
                pb[r] = (_Float16)fmaf(re, re, im*im);                         \
            }                                                                  \
            d2 = __builtin_amdgcn_mfma_f32_16x16x16f16(a2[c2], pb, d2, 0,0,0); \
        }                                                                      \
        const float ssv = __shfl_xor(d2[0], 16, 64);                           \
        if (quad == 0) {                                                       \
            const float inv = 1.0f / ssv;                                      \
            float4 o;                                                          \
            o.x = fmaf(d2[0], inv, b0);                                        \
            o.y = fmaf(d2[1], inv, b1);                                        \
            o.z = fmaf(d2[2], inv, b2);                                        \
            o.w = fmaf(d2[3], inv, b3);                                        \
            *(float4*)(out + (gw*TPW + (TI))*16*4 + (size_t)l15*4) = o;        \
        }                                                                      \
    }

    #pragma clang loop unroll(disable)
    for (int t = 0; t < TPW; t += 2) {
        // prefetch tile t+1 -> buffer 1
        {
            const float* xt = xbase + (size_t)(t + 1) * 1024;
            xr[1][0] = *(const float4*)(xt);
            xr[1][1] = *(const float4*)(xt + 4);
            xr[1][2] = *(const float4*)(xt + 32);
            xr[1][3] = *(const float4*)(xt + 36);
        }
        QNN_COMPUTE(0, t)
        // prefetch tile t+2 -> buffer 0 (clamped; last round reloads tile TPW-1)
        {
            const int tn = (t + 2 < TPW) ? (t + 2) : (TPW - 1);
            const float* xt = xbase + (size_t)tn * 1024;
            xr[0][0] = *(const float4*)(xt);
            xr[0][1] = *(const float4*)(xt + 4);
            xr[0][2] = *(const float4*)(xt + 32);
            xr[0][3] = *(const float4*)(xt + 36);
        }
        QNN_COMPUTE(1, t + 1)
    }
#undef QNN_COMPUTE
}

extern "C" void kernel_launch(void* const* d_in, const int* in_sizes, int n_in,
                              void* d_out, int out_size, void* d_ws, size_t ws_size,
                              hipStream_t stream) {
    const float* x    = (const float*)d_in[0];   // [262144, 64]
    const float* wts  = (const float*)d_in[1];   // [8, 6, 3]
    const float* fc_w = (const float*)d_in[2];   // [4, 6]
    const float* fc_b = (const float*)d_in[3];   // [4]
    float* out = (float*)d_out;                  // [262144, 4]

    // 512 blocks x 4 waves x TPW(8) tiles x 16 samples = 262144
    qnn_prep<<<DIM, DIM, 0, stream>>>(wts, fc_w, d_ws);
    qnn_main<<<512, 256, 0, stream>>>(x, fc_b, d_ws, out);
}

// Round 7
// 108.779 us; speedup vs baseline: 1.0153x; 1.0153x over previous
//
#include <hip/hip_runtime.h>

#define NQ 6
#define DIM 64
#define NL 8

#define WP  72    // W f16 row pitch in ws (144 B rows, 16B-aligned)
#define XP  68    // per-sample f16 pitch in LDS stage (136 B)
#define TPW 4     // tiles of 32 samples per wave; 512 blk x 4 waves x 4 x 32 = 262144

typedef __attribute__((ext_vector_type(4))) float    floatx4;
typedef __attribute__((ext_vector_type(4))) _Float16 half4v;   // 4 f16 = 2 VGPRs

// ---------------------------------------------------------------------------
// Prep (circuit verified rounds 1-6): build unitary U, emit to ws:
//   Wf[128][WP] f16 : rows n<64 = Re(U)[n][*], n>=64 = Im(U)[n-64][*]
//   M5h table (f16) at byte offset 128*WP*2: A-fragment-ready for
//   mfma_f32_16x16x16f16: entry [c2][lane][j] = M5[c2*16+(lane>>4)*4+j][lane&15]
//   where M5[i][c<4] = sum_q sign(i,q) fc_w[c][q], M5[i][4] = 1, else 0.
// ---------------------------------------------------------------------------
__global__ __launch_bounds__(64) void qnn_prep(
    const float* __restrict__ wts,   // [8*6*3] (phi, theta, omega)
    const float* __restrict__ fc_w,  // [4*6]
    void* __restrict__ ws)
{
    __shared__ float gc[48][4];
    const int n   = threadIdx.x;     // amplitude row 0..63
    const int col = blockIdx.x;      // basis column 0..63

    if (n < 48) {
        float phi = wts[n*3+0], th = wts[n*3+1], om = wts[n*3+2];
        float ch = cosf(0.5f*th), sh = sinf(0.5f*th);
        float p  = 0.5f*(phi+om), m  = 0.5f*(phi-om);
        gc[n][0] = cosf(p)*ch;
        gc[n][1] = sinf(p)*ch;
        gc[n][2] = cosf(m)*sh;
        gc[n][3] = sinf(m)*sh;
    }
    __syncthreads();

    float ar = (n == col) ? 1.0f : 0.0f;
    float ai = 0.0f;

    #pragma unroll
    for (int l = 0; l < NL; ++l) {
        #pragma unroll
        for (int q = 0; q < NQ; ++q) {
            const int g     = l*NQ + q;
            const int shift = 5 - q;
            const int mask  = 1 << shift;
            const int b     = (n >> shift) & 1;
            const float cpch = gc[g][0];
            const float spch = gc[g][1];
            const float cmsh = gc[g][2];
            const float smsh = gc[g][3];
            const float pr = __shfl_xor(ar, mask, 64);
            const float pi = __shfl_xor(ai, mask, 64);
            const float udr = cpch;
            const float udi = b ?  spch : -spch;
            const float uor = b ?  cmsh : -cmsh;
            const float uoi = -smsh;
            const float nr = udr*ar - udi*ai + uor*pr - uoi*pi;
            const float ni = udr*ai + udi*ar + uor*pi + uoi*pr;
            ar = nr; ai = ni;
        }
        const int r = (l % (NQ - 1)) + 1;
        #pragma unroll
        for (int q = 0; q < NQ; ++q) {
            const int t     = (q + r) % NQ;
            const int cmask = 1 << (5 - q);
            const int tmask = 1 << (5 - t);
            const float pr = __shfl_xor(ar, tmask, 64);
            const float pi = __shfl_xor(ai, tmask, 64);
            const bool ctrl = (n & cmask) != 0;
            ar = ctrl ? pr : ar;
            ai = ctrl ? pi : ai;
        }
    }

    _Float16* Wf = (_Float16*)ws;
    Wf[n*WP + col]      = (_Float16)ar;
    Wf[(64+n)*WP + col] = (_Float16)ai;

    if (col == 0) {
        const int cp = n & 15;            // c' = l15
        const int qd = n >> 4;            // quad
        half4v* Mo = (half4v*)((char*)ws + 128*WP*2);
        #pragma unroll
        for (int c2 = 0; c2 < 4; ++c2) {
            half4v h4;
            #pragma unroll
            for (int j = 0; j < 4; ++j) {
                const int i = c2*16 + qd*4 + j;
                float v = 0.f;
                if (cp < 4) {
                    #pragma unroll
                    for (int q = 0; q < NQ; ++q) {
                        const float sgn = 1.0f - 2.0f*(float)((i >> (5-q)) & 1);
                        v = fmaf(sgn, fc_w[cp*NQ + q], v);
                    }
                } else if (cp == 4) {
                    v = 1.0f;             // ones column -> ss
                }
                h4[j] = (_Float16)v;
            }
            Mo[c2*64 + n] = h4;
        }
    }
}

// ---------------------------------------------------------------------------
// Main: 512 blocks x 256 thr (2 blocks/CU). NO barriers after launch prologue
// is even needed: LDS is used only as per-WAVE transpose scratch.
// Wave holds all W fragments (f16, 32 x half4v = 64 VGPRs) + M5 fragments in
// registers; per 32-sample tile: 8 fully-coalesced float4 loads (1 KB/instr)
// -> f16 convert -> wave-private LDS stage -> b64 fragment reads ->
// 64x mfma_f32_16x16x16f16 (K=64, re+im) -> f16-MFMA epilogue -> store.
// Double-buffered: tile t+1's global loads issue before tile t's compute.
// ---------------------------------------------------------------------------
__global__ __launch_bounds__(256, 2) void qnn_main(
    const float* __restrict__ x,
    const float* __restrict__ fc_b,
    const void* __restrict__ wsv,
    float* __restrict__ out)
{
    __shared__ __align__(16) _Float16 Xs[8][32*XP];   // [w*2+buf], 4352 B each

    const int tid  = threadIdx.x;
    const int lane = tid & 63;
    const int w    = tid >> 6;
    const int l15  = lane & 15;
    const int quad = lane >> 4;
    const size_t gw = (size_t)blockIdx.x*4 + w;       // 0..2047

    // --- W fragments: A-layout, wfr[kc][mt][j] = W[mt*16+l15][kc*16+quad*4+j]
    const _Float16* Wf = (const _Float16*)wsv;
    half4v wfr[4][8];
    #pragma unroll
    for (int kc = 0; kc < 4; ++kc)
        #pragma unroll
        for (int mt = 0; mt < 8; ++mt)
            wfr[kc][mt] = *(const half4v*)(Wf + (mt*16 + l15)*WP + kc*16 + quad*4);

    // --- M5 epilogue A-fragments ---
    const half4v* Mg = (const half4v*)((const char*)wsv + 128*WP*2);
    half4v a2[4];
    #pragma unroll
    for (int c2 = 0; c2 < 4; ++c2) a2[c2] = Mg[c2*64 + lane];

    const float b0 = fc_b[0], b1 = fc_b[1], b2 = fc_b[2], b3 = fc_b[3];

    const float* xw = x + gw*(TPW*32)*DIM;            // wave's 128-sample span

#define QNN_LOAD(XRV, TI)                                                      \
    {                                                                          \
        const float* xb = xw + (size_t)(TI)*32*DIM;                            \
        _Pragma("unroll")                                                      \
        for (int i = 0; i < 8; ++i)                                            \
            XRV[i] = *(const float4*)(xb + i*256 + lane*4);                    \
    }

#define QNN_STAGE(XRV, BUF)                                                    \
    {                                                                          \
        _Float16* XsR = &Xs[w*2 + (BUF)][0];                                   \
        _Pragma("unroll")                                                      \
        for (int i = 0; i < 8; ++i) {                                          \
            const int ls = 4*i + quad;                                         \
            half4v h;                                                          \
            h[0] = (_Float16)XRV[i].x; h[1] = (_Float16)XRV[i].y;              \
            h[2] = (_Float16)XRV[i].z; h[3] = (_Float16)XRV[i].w;              \
            *(half4v*)&XsR[ls*XP + 4*l15] = h;                                 \
        }                                                                      \
    }

#define QNN_COMPUTE(BUF, TI)                                                   \
    {                                                                          \
        const _Float16* XsR = &Xs[w*2 + (BUF)][0];                             \
        half4v xf[2][4];                                                       \
        _Pragma("unroll")                                                      \
        for (int st = 0; st < 2; ++st)                                         \
            _Pragma("unroll")                                                  \
            for (int kc = 0; kc < 4; ++kc)                                     \
                xf[st][kc] = *(const half4v*)                                  \
                    &XsR[(st*16 + l15)*XP + kc*16 + quad*4];                   \
        _Pragma("unroll")                                                      \
        for (int st = 0; st < 2; ++st) {                                       \
            floatx4 acc[8];                                                    \
            _Pragma("unroll")                                                  \
            for (int mt = 0; mt < 8; ++mt)                                     \
                acc[mt] = (floatx4){0.f, 0.f, 0.f, 0.f};                       \
            _Pragma("unroll")                                                  \
            for (int kc = 0; kc < 4; ++kc)                                     \
                _Pragma("unroll")                                              \
                for (int mt = 0; mt < 8; ++mt)                                 \
                    acc[mt] = __builtin_amdgcn_mfma_f32_16x16x16f16(           \
                        wfr[kc][mt], xf[st][kc], acc[mt], 0, 0, 0);            \
            floatx4 d2 = (floatx4){0.f, 0.f, 0.f, 0.f};                        \
            _Pragma("unroll")                                                  \
            for (int c2 = 0; c2 < 4; ++c2) {                                   \
                half4v pb;                                                     \
                _Pragma("unroll")                                              \
                for (int r = 0; r < 4; ++r) {                                  \
                    const float re = acc[c2][r];                               \
                    const float im = acc[c2 + 4][r];                           \
                    pb[r] = (_Float16)fmaf(re, re, im*im);                     \
                }                                                              \
                d2 = __builtin_amdgcn_mfma_f32_16x16x16f16(a2[c2], pb, d2,     \
                                                           0, 0, 0);           \
            }                                                                  \
            const float ssv = __shfl_xor(d2[0], 16, 64);                       \
            if (quad == 0) {                                                   \
                const float inv = 1.0f / ssv;                                  \
                float4 o;                                                      \
                o.x = fmaf(d2[0], inv, b0);                                    \
                o.y = fmaf(d2[1], inv, b1);                                    \
                o.z = fmaf(d2[2], inv, b2);                                    \
                o.w = fmaf(d2[3], inv, b3);                                    \
                *(float4*)(out +                                               \
                    (gw*(TPW*32) + (size_t)(TI)*32 + st*16 + l15)*4) = o;      \
            }                                                                  \
        }                                                                      \
    }

    float4 xa[8], xb4[8];

    QNN_LOAD(xa, 0)
    QNN_STAGE(xa, 0)

    QNN_LOAD(xb4, 1)      // tile 1 in flight during tile 0 compute
    QNN_COMPUTE(0, 0)
    QNN_STAGE(xb4, 1)

    QNN_LOAD(xa, 2)
    QNN_COMPUTE(1, 1)
    QNN_STAGE(xa, 0)

    QNN_LOAD(xb4, 3)
    QNN_COMPUTE(0, 2)
    QNN_STAGE(xb4, 1)

    QNN_COMPUTE(1, 3)

#undef QNN_LOAD
#undef QNN_STAGE
#undef QNN_COMPUTE
}

extern "C" void kernel_launch(void* const* d_in, const int* in_sizes, int n_in,
                              void* d_out, int out_size, void* d_ws, size_t ws_size,
                              hipStream_t stream) {
    const float* x    = (const float*)d_in[0];   // [262144, 64]
    const float* wts  = (const float*)d_in[1];   // [8, 6, 3]
    const float* fc_w = (const float*)d_in[2];   // [4, 6]
    const float* fc_b = (const float*)d_in[3];   // [4]
    float* out = (float*)d_out;                  // [262144, 4]

    qnn_prep<<<DIM, DIM, 0, stream>>>(wts, fc_w, d_ws);
    qnn_main<<<512, 256, 0, stream>>>(x, fc_b, d_ws, out);
}